// Round 4
// baseline (159.770 us; speedup 1.0000x reference)
//
#include <hip/hip_runtime.h>
#include <stdint.h>

#define NB 8
#define ND 2048
#define NH 256

typedef __attribute__((ext_vector_type(8))) short bf16x8;
typedef __attribute__((ext_vector_type(4))) float f32x4;
typedef __attribute__((ext_vector_type(4))) int   i32x4;
typedef __attribute__((ext_vector_type(2))) unsigned int u32x2;
typedef __attribute__((ext_vector_type(4))) unsigned int u32x4;

#define MFMA16 __builtin_amdgcn_mfma_f32_16x16x32_bf16

__device__ __forceinline__ unsigned short f2bf(float f) {
    union { float f; unsigned int u; } c; c.f = f;
    unsigned int u = c.u + 0x7FFFu + ((c.u >> 16) & 1u);
    return (unsigned short)(u >> 16);
}
__device__ __forceinline__ unsigned int pack2(float a, float b) {
    return (unsigned int)f2bf(a) | ((unsigned int)f2bf(b) << 16);
}

__device__ __forceinline__ void gload_lds16(const void* g, void* l) {
    __builtin_amdgcn_global_load_lds(
        (const __attribute__((address_space(1))) void*)g,
        (__attribute__((address_space(3))) void*)l, 16, 0, 0);
}

// ---------------------------------------------------------------------------
// Kernel 1: q = x@Wq^T, k = x@Wk^T (row-major bf16), vT[o][d] = (x@Wv^T)^T
// ---------------------------------------------------------------------------
__global__ __launch_bounds__(256) void qkv_kernel(
    const float* __restrict__ x,
    const float* __restrict__ Wq, const float* __restrict__ Wk, const float* __restrict__ Wv,
    unsigned short* __restrict__ qb, unsigned short* __restrict__ kb, unsigned short* __restrict__ vT)
{
    __shared__ unsigned short Wt[64][264];
    __shared__ unsigned short Xt[64][264];
    const int z  = blockIdx.z;
    const int m0 = blockIdx.x * 64;
    const int o0 = blockIdx.y * 64;
    const float* W = (z == 0) ? Wq : (z == 1 ? Wk : Wv);
    const int t = threadIdx.x;

#pragma unroll
    for (int i = 0; i < 16; ++i) {
        int fidx = i * 256 + t;
        int row = fidx >> 6, c4 = fidx & 63;
        f32x4 vW = *reinterpret_cast<const f32x4*>(W + (size_t)(o0 + row) * NH + c4 * 4);
        f32x4 vX = *reinterpret_cast<const f32x4*>(x + (size_t)(m0 + row) * NH + c4 * 4);
        u32x2 pw; pw[0] = pack2(vW[0], vW[1]); pw[1] = pack2(vW[2], vW[3]);
        u32x2 px; px[0] = pack2(vX[0], vX[1]); px[1] = pack2(vX[2], vX[3]);
        *reinterpret_cast<u32x2*>(&Wt[row][c4 * 4]) = pw;
        *reinterpret_cast<u32x2*>(&Xt[row][c4 * 4]) = px;
    }
    __syncthreads();

    const int w = t >> 6, lane = t & 63, lr = lane & 15, half = lane >> 4;
    const unsigned short (*Ab)[264] = (z < 2) ? Wt : Xt;
    const unsigned short (*Bb)[264] = (z < 2) ? Xt : Wt;
    const int ar0 = 32 * (w >> 1), br0 = 32 * (w & 1);

    f32x4 acc[2][2] = {};
#pragma unroll
    for (int kk = 0; kk < 8; ++kk) {
        bf16x8 a[2], bfr[2];
#pragma unroll
        for (int f = 0; f < 2; ++f) {
            a[f]   = *reinterpret_cast<const bf16x8*>(&Ab[ar0 + 16 * f + lr][32 * kk + 8 * half]);
            bfr[f] = *reinterpret_cast<const bf16x8*>(&Bb[br0 + 16 * f + lr][32 * kk + 8 * half]);
        }
#pragma unroll
        for (int fa = 0; fa < 2; ++fa)
#pragma unroll
            for (int fb = 0; fb < 2; ++fb)
                acc[fa][fb] = MFMA16(a[fa], bfr[fb], acc[fa][fb], 0, 0, 0);
    }

    if (z < 2) {
        unsigned short* dst = z ? kb : qb;
#pragma unroll
        for (int fa = 0; fa < 2; ++fa)
#pragma unroll
            for (int fb = 0; fb < 2; ++fb) {
                int m = m0 + br0 + 16 * fb + lr;
                int o = o0 + ar0 + 16 * fa + 4 * half;
                u32x2 pk; pk[0] = pack2(acc[fa][fb][0], acc[fa][fb][1]);
                pk[1] = pack2(acc[fa][fb][2], acc[fa][fb][3]);
                *reinterpret_cast<u32x2*>(dst + (size_t)m * NH + o) = pk;
            }
    } else {
#pragma unroll
        for (int fa = 0; fa < 2; ++fa)
#pragma unroll
            for (int fb = 0; fb < 2; ++fb) {
                int dg = m0 + ar0 + 16 * fa + 4 * half;
                int o  = o0 + br0 + 16 * fb + lr;
                int bb = dg >> 11, di = dg & 2047;
                u32x2 pk; pk[0] = pack2(acc[fa][fb][0], acc[fa][fb][1]);
                pk[1] = pack2(acc[fa][fb][2], acc[fa][fb][3]);
                *reinterpret_cast<u32x2*>(vT + ((size_t)bb * NH + o) * ND + di) = pk;
            }
    }
}

// ---------------------------------------------------------------------------
// Kernel 2: flash attention partials over an e-half.
// grid 256: b = bid&7 (XCD), eh = (bid>>3)&1 (e-half), qt = bid>>4 (128 q-rows).
// 8 waves: pair pr = w&3 owns 32 q-rows (2 d-frags); side = w>>2 splits PV fo.
// Each K/V LDS fragment read feeds 2 MFMA (dq reuse). Partials (bf16 acc,
// f32 m/l) -> ws; combine_kernel merges the two e-halves.
// ---------------------------------------------------------------------------
__global__ __launch_bounds__(512, 2) void attn_kernel(
    const unsigned short* __restrict__ qb, const unsigned short* __restrict__ kb,
    const unsigned short* __restrict__ vT, const int* __restrict__ adj,
    unsigned short* __restrict__ part, float* __restrict__ mpart, float* __restrict__ lpart)
{
    __shared__ unsigned char KT[2][32768];   // [64 e][512 B], swizzled
    __shared__ unsigned char VTl[2][32768];  // [256 o][128 B], swizzled
    __shared__ unsigned short P[8][2][16][64]; // per-wave per-dq, XOR-swizzled

    const int bid = blockIdx.x;
    const int b = bid & 7, eh = (bid >> 3) & 1, qt = bid >> 4;
    const int t = threadIdx.x, w = t >> 6, lane = t & 63, lr = lane & 15, half = lane >> 4;
    const int pr = w & 3, side = w >> 2;
    const int qbase = qt * 128 + pr * 32;
    const int swz = (lr & 7) << 4;

    bf16x8 qf[2][8];
#pragma unroll
    for (int dq = 0; dq < 2; ++dq) {
        const size_t qrow = ((size_t)b * ND + qbase + dq * 16 + lr) * NH;
#pragma unroll
        for (int kk = 0; kk < 8; ++kk)
            qf[dq][kk] = *reinterpret_cast<const bf16x8*>(qb + qrow + 32 * kk + 8 * half);
    }

    const char* kbc = (const char*)kb + (size_t)b * ND * 512 + (size_t)eh * 1024 * 512;
    const char* vtc = (const char*)vT + (size_t)b * NH * ND * 2 + (size_t)eh * 1024 * 2;
    const int* adjr0 = adj + ((size_t)b * ND + qbase + lr) * ND + eh * 1024;
    const int* adjr1 = adjr0 + (size_t)16 * ND;

    auto stageK = [&](int buf, int e0s) {
#pragma unroll
        for (int i = 0; i < 4; ++i) {
            int off = w * 4096 + i * 1024 + lane * 16;
            int r = off >> 9;
            int c = off & 511;
            int src = c ^ ((r & 7) << 4);
            gload_lds16(kbc + (size_t)(e0s + r) * 512 + src,
                        &KT[buf][w * 4096 + i * 1024]);
        }
    };
    auto stageV = [&](int buf, int e0s) {
#pragma unroll
        for (int i = 0; i < 4; ++i) {
            int off = w * 4096 + i * 1024 + lane * 16;
            int o = off >> 7;
            int c = off & 127;
            int src = c ^ ((o & 7) << 4);
            gload_lds16(vtc + (size_t)o * (ND * 2) + e0s * 2 + src,
                        &VTl[buf][w * 4096 + i * 1024]);
        }
    };

    f32x4 acc[2][8] = {};
    float m_run[2] = {-__builtin_inff(), -__builtin_inff()};
    float l_run[2] = {0.f, 0.f};
    const float SC = 0.0625f, L2E = 1.44269504f;

    stageK(0, 0);
    stageV(0, 0);
    __syncthreads();

    for (int tt = 0; tt < 16; ++tt) {
        const int cur = tt & 1;
        if (tt < 15) {
            stageK(cur ^ 1, (tt + 1) * 64);
            stageV(cur ^ 1, (tt + 1) * 64);
        }
        // adj for this tile (latency hides under QK)
        i32x4 aj[2][4];
#pragma unroll
        for (int fe = 0; fe < 4; ++fe) {
            aj[0][fe] = *reinterpret_cast<const i32x4*>(adjr0 + tt * 64 + fe * 16 + 4 * half);
            aj[1][fe] = *reinterpret_cast<const i32x4*>(adjr1 + tt * 64 + fe * 16 + 4 * half);
        }

        // ---- QK^T: each K frag feeds both d-frags ----
        const char* Kc = (const char*)&KT[cur][0];
        f32x4 s[2][4] = {};
#pragma unroll
        for (int kk = 0; kk < 8; ++kk)
#pragma unroll
            for (int fe = 0; fe < 4; ++fe) {
                bf16x8 kf = *reinterpret_cast<const bf16x8*>(
                    Kc + (fe * 16 + lr) * 512 + ((kk * 64 + half * 16) ^ swz));
                s[0][fe] = MFMA16(kf, qf[0][kk], s[0][fe], 0, 0, 0);
                s[1][fe] = MFMA16(kf, qf[1][kk], s[1][fe], 0, 0, 0);
            }

        // ---- mask + online softmax per d-frag (defer-max) ----
#pragma unroll
        for (int dq = 0; dq < 2; ++dq) {
            float pv[4][4];
            float tmax = -__builtin_inff();
#pragma unroll
            for (int fe = 0; fe < 4; ++fe)
#pragma unroll
                for (int r = 0; r < 4; ++r) {
                    float sv = s[dq][fe][r] * SC;
                    sv = (aj[dq][fe][r] > 0) ? sv : -1e9f;
                    pv[fe][r] = sv;
                    tmax = fmaxf(tmax, sv);
                }
            tmax = fmaxf(tmax, __shfl_xor(tmax, 16));
            tmax = fmaxf(tmax, __shfl_xor(tmax, 32));

            if (!__all(tmax <= m_run[dq] + 8.0f)) {
                const float m_new = fmaxf(m_run[dq], tmax);
                const float scale = exp2f((m_run[dq] - m_new) * L2E);
#pragma unroll
                for (int j = 0; j < 8; ++j)
#pragma unroll
                    for (int r = 0; r < 4; ++r) acc[dq][j][r] *= scale;
                l_run[dq] *= scale;
                m_run[dq] = m_new;
            }
            float psum = 0.f;
#pragma unroll
            for (int fe = 0; fe < 4; ++fe)
#pragma unroll
                for (int r = 0; r < 4; ++r) {
                    float pe = exp2f((pv[fe][r] - m_run[dq]) * L2E);
                    pv[fe][r] = pe;
                    psum += pe;
                }
            psum += __shfl_xor(psum, 16);
            psum += __shfl_xor(psum, 32);
            l_run[dq] += psum;

            // P -> per-wave swizzled LDS (row = lr, 128B stride)
            char* Pb = (char*)&P[w][dq][0][0] + lr * 128;
#pragma unroll
            for (int fe = 0; fe < 4; ++fe) {
                u32x2 pk; pk[0] = pack2(pv[fe][0], pv[fe][1]); pk[1] = pack2(pv[fe][2], pv[fe][3]);
                *reinterpret_cast<u32x2*>(Pb + ((fe * 32 + half * 8) ^ swz)) = pk;
            }
        }

        bf16x8 pf[2][2];
#pragma unroll
        for (int dq = 0; dq < 2; ++dq) {
            const char* Pb = (const char*)&P[w][dq][0][0] + lr * 128;
#pragma unroll
            for (int es = 0; es < 2; ++es)
                pf[dq][es] = *reinterpret_cast<const bf16x8*>(Pb + ((es * 64 + half * 16) ^ swz));
        }

        // ---- PV: each V frag feeds both d-frags; fo split by side ----
        const char* Vc = (const char*)&VTl[cur][0];
#pragma unroll
        for (int j = 0; j < 8; ++j) {
            const int fo = side * 8 + j;
#pragma unroll
            for (int es = 0; es < 2; ++es) {
                bf16x8 vf = *reinterpret_cast<const bf16x8*>(
                    Vc + (fo * 16 + lr) * 128 + ((es * 64 + half * 16) ^ swz));
                acc[0][j] = MFMA16(vf, pf[0][es], acc[0][j], 0, 0, 0);
                acc[1][j] = MFMA16(vf, pf[1][es], acc[1][j], 0, 0, 0);
            }
        }
        __syncthreads();
    }

    // ---- epilogue: unnormalized bf16 partials + m/l ----
#pragma unroll
    for (int dq = 0; dq < 2; ++dq) {
        const int qg = b * ND + qbase + dq * 16 + lr;
        const size_t pbase = ((size_t)eh * 16384 + qg) * 256;
#pragma unroll
        for (int j = 0; j < 8; ++j) {
            const int fo = side * 8 + j;
            u32x2 pk; pk[0] = pack2(acc[dq][j][0], acc[dq][j][1]);
            pk[1] = pack2(acc[dq][j][2], acc[dq][j][3]);
            *reinterpret_cast<u32x2*>(part + pbase + fo * 16 + 4 * half) = pk;
        }
        if (half == 0 && side == 0) {
            mpart[eh * 16384 + qg] = m_run[dq];
            lpart[eh * 16384 + qg] = l_run[dq];
        }
    }
}

// ---------------------------------------------------------------------------
// Kernel 2b: combine the two e-half partials -> agg (bf16).
// ---------------------------------------------------------------------------
__global__ __launch_bounds__(256) void combine_kernel(
    const unsigned short* __restrict__ part, const float* __restrict__ mpart,
    const float* __restrict__ lpart, unsigned short* __restrict__ agg)
{
    const int t = threadIdx.x, w = t >> 6, lane = t & 63;
    const int q = blockIdx.x * 4 + w;
    const float L2E = 1.44269504f;
    const float m0 = mpart[q], m1 = mpart[16384 + q];
    const float l0 = lpart[q], l1 = lpart[16384 + q];
    const float mm = fmaxf(m0, m1);
    const float s0 = exp2f((m0 - mm) * L2E);
    const float s1 = exp2f((m1 - mm) * L2E);
    const float inv = 1.f / (s0 * l0 + s1 * l1);

    u32x2 a = *reinterpret_cast<const u32x2*>(part + (size_t)q * 256 + lane * 4);
    u32x2 c = *reinterpret_cast<const u32x2*>(part + (size_t)(16384 + q) * 256 + lane * 4);
    float av[4], cv[4];
    av[0] = __uint_as_float(a[0] << 16); av[1] = __uint_as_float(a[0] & 0xffff0000u);
    av[2] = __uint_as_float(a[1] << 16); av[3] = __uint_as_float(a[1] & 0xffff0000u);
    cv[0] = __uint_as_float(c[0] << 16); cv[1] = __uint_as_float(c[0] & 0xffff0000u);
    cv[2] = __uint_as_float(c[1] << 16); cv[3] = __uint_as_float(c[1] & 0xffff0000u);
    float o[4];
#pragma unroll
    for (int r = 0; r < 4; ++r) o[r] = (s0 * av[r] + s1 * cv[r]) * inv;
    u32x2 pk; pk[0] = pack2(o[0], o[1]); pk[1] = pack2(o[2], o[3]);
    *reinterpret_cast<u32x2*>(agg + (size_t)q * 256 + lane * 4) = pk;
}

// ---------------------------------------------------------------------------
// Kernel 3a: h = agg @ Wp^T + bp + x   (f32 out)
// ---------------------------------------------------------------------------
__global__ __launch_bounds__(256) void oproj_kernel(
    const unsigned short* __restrict__ agg, const float* __restrict__ Wp,
    const float* __restrict__ bp, const float* __restrict__ x, float* __restrict__ h)
{
    __shared__ unsigned short Wt[64][264];
    __shared__ unsigned short Xt[64][264];
    const int m0 = blockIdx.x * 64, p0 = blockIdx.y * 64;
    const int t = threadIdx.x;

#pragma unroll
    for (int i = 0; i < 16; ++i) {
        int fidx = i * 256 + t, row = fidx >> 6, c4 = fidx & 63;
        f32x4 vW = *reinterpret_cast<const f32x4*>(Wp + (size_t)(p0 + row) * NH + c4 * 4);
        u32x2 pw; pw[0] = pack2(vW[0], vW[1]); pw[1] = pack2(vW[2], vW[3]);
        *reinterpret_cast<u32x2*>(&Wt[row][c4 * 4]) = pw;
    }
#pragma unroll
    for (int i = 0; i < 8; ++i) {
        int fidx = i * 256 + t, row = fidx >> 5, c8 = fidx & 31;
        u32x4 vA = *reinterpret_cast<const u32x4*>(agg + (size_t)(m0 + row) * NH + c8 * 8);
        *reinterpret_cast<u32x4*>(&Xt[row][c8 * 8]) = vA;
    }
    __syncthreads();

    const int w = t >> 6, lane = t & 63, lr = lane & 15, half = lane >> 4;
    const int ar0 = 32 * (w >> 1), br0 = 32 * (w & 1);

    f32x4 acc[2][2] = {};
#pragma unroll
    for (int kk = 0; kk < 8; ++kk) {
        bf16x8 a[2], bfr[2];
#pragma unroll
        for (int f = 0; f < 2; ++f) {
            a[f]   = *reinterpret_cast<const bf16x8*>(&Wt[ar0 + 16 * f + lr][32 * kk + 8 * half]);
            bfr[f] = *reinterpret_cast<const bf16x8*>(&Xt[br0 + 16 * f + lr][32 * kk + 8 * half]);
        }
#pragma unroll
        for (int fa = 0; fa < 2; ++fa)
#pragma unroll
            for (int fb = 0; fb < 2; ++fb)
                acc[fa][fb] = MFMA16(a[fa], bfr[fb], acc[fa][fb], 0, 0, 0);
    }

#pragma unroll
    for (int fa = 0; fa < 2; ++fa)
#pragma unroll
        for (int fb = 0; fb < 2; ++fb) {
            int pcol = p0 + ar0 + 16 * fa + 4 * half;
            int m = m0 + br0 + 16 * fb + lr;
            f32x4 bias = *reinterpret_cast<const f32x4*>(bp + pcol);
            f32x4 xr   = *reinterpret_cast<const f32x4*>(x + (size_t)m * NH + pcol);
            f32x4 out;
#pragma unroll
            for (int r = 0; r < 4; ++r) out[r] = acc[fa][fb][r] + bias[r] + xr[r];
            *reinterpret_cast<f32x4*>(h + (size_t)m * NH + pcol) = out;
        }
}

// ---------------------------------------------------------------------------
// Kernel 3b: LayerNorm rows of h -> out.
// ---------------------------------------------------------------------------
__global__ __launch_bounds__(256) void ln_kernel(
    const float* __restrict__ h, const float* __restrict__ gamma,
    const float* __restrict__ beta, float* __restrict__ out)
{
    const int t = threadIdx.x, w = t >> 6, lane = t & 63;
    const size_t row = (size_t)blockIdx.x * 4 + w;
    const float* hr = h + row * NH;
    f32x4 v = *reinterpret_cast<const f32x4*>(hr + lane * 4);
    float s = v[0] + v[1] + v[2] + v[3];
#pragma unroll
    for (int off = 1; off < 64; off <<= 1) s += __shfl_xor(s, off);
    const float mu = s * (1.f / 256.f);
    f32x4 dv; float q = 0.f;
#pragma unroll
    for (int r = 0; r < 4; ++r) { dv[r] = v[r] - mu; q += dv[r] * dv[r]; }
#pragma unroll
    for (int off = 1; off < 64; off <<= 1) q += __shfl_xor(q, off);
    const float rs = rsqrtf(q * (1.f / 256.f) + 1e-5f);
    f32x4 g  = *reinterpret_cast<const f32x4*>(gamma + lane * 4);
    f32x4 be = *reinterpret_cast<const f32x4*>(beta + lane * 4);
    f32x4 o;
#pragma unroll
    for (int r = 0; r < 4; ++r) o[r] = dv[r] * rs * g[r] + be[r];
    *reinterpret_cast<f32x4*>(out + row * NH + lane * 4) = o;
}

extern "C" void kernel_launch(void* const* d_in, const int* in_sizes, int n_in,
                              void* d_out, int out_size, void* d_ws, size_t ws_size,
                              hipStream_t stream)
{
    const float* x     = (const float*)d_in[0];
    const int*   adj   = (const int*)d_in[1];
    const float* Wq    = (const float*)d_in[2];
    const float* Wk    = (const float*)d_in[3];
    const float* Wv    = (const float*)d_in[4];
    const float* Wp    = (const float*)d_in[5];
    const float* bp    = (const float*)d_in[6];
    const float* gamma = (const float*)d_in[7];
    const float* beta  = (const float*)d_in[8];

    char* ws = (char*)d_ws;
    const size_t MB = 1024 * 1024;
    // 0-8M: q / agg (overlay)   8-16M: k   16-24M: vT
    // 24-40M: attn partials (2 x 8MB bf16)   40M-+256K: m/l partials
    // 8-24M: h (f32, after attn+combine)
    unsigned short* qb    = (unsigned short*)(ws);
    unsigned short* kb    = (unsigned short*)(ws + 8 * MB);
    unsigned short* vT    = (unsigned short*)(ws + 16 * MB);
    unsigned short* agg   = qb;
    unsigned short* partb = (unsigned short*)(ws + 24 * MB);
    float* mpart = (float*)(ws + 40 * MB);
    float* lpart = (float*)(ws + 40 * MB + 128 * 1024);
    float* h = (float*)(ws + 8 * MB);
    float* out = (float*)d_out;

    qkv_kernel<<<dim3(256, 4, 3), 256, 0, stream>>>(x, Wq, Wk, Wv, qb, kb, vT);
    attn_kernel<<<dim3(256), 512, 0, stream>>>(qb, kb, vT, adj, partb, mpart, lpart);
    combine_kernel<<<dim3(4096), 256, 0, stream>>>(partb, mpart, lpart, agg);
    oproj_kernel<<<dim3(256, 4), 256, 0, stream>>>(agg, Wp, bp, x, h);
    ln_kernel<<<dim3(4096), 256, 0, stream>>>(h, gamma, beta, out);
}

// Round 5
// 149.804 us; speedup vs baseline: 1.0665x; 1.0665x over previous
//
#include <hip/hip_runtime.h>
#include <stdint.h>

#define NB 8
#define ND 2048
#define NH 256

typedef __attribute__((ext_vector_type(8))) short bf16x8;
typedef __attribute__((ext_vector_type(4))) float f32x4;
typedef __attribute__((ext_vector_type(4))) int   i32x4;
typedef __attribute__((ext_vector_type(2))) unsigned int u32x2;
typedef __attribute__((ext_vector_type(4))) unsigned int u32x4;

#define MFMA16 __builtin_amdgcn_mfma_f32_16x16x32_bf16

__device__ __forceinline__ unsigned short f2bf(float f) {
    union { float f; unsigned int u; } c; c.f = f;
    unsigned int u = c.u + 0x7FFFu + ((c.u >> 16) & 1u);
    return (unsigned short)(u >> 16);
}
__device__ __forceinline__ unsigned int pack2(float a, float b) {
    return (unsigned int)f2bf(a) | ((unsigned int)f2bf(b) << 16);
}

__device__ __forceinline__ void gload_lds16(const void* g, void* l) {
    __builtin_amdgcn_global_load_lds(
        (const __attribute__((address_space(1))) void*)g,
        (__attribute__((address_space(3))) void*)l, 16, 0, 0);
}

// ---------------------------------------------------------------------------
// Kernel 1: q = x@Wq^T, k = x@Wk^T (row-major bf16), vT[o][d] = (x@Wv^T)^T
// ---------------------------------------------------------------------------
__global__ __launch_bounds__(256) void qkv_kernel(
    const float* __restrict__ x,
    const float* __restrict__ Wq, const float* __restrict__ Wk, const float* __restrict__ Wv,
    unsigned short* __restrict__ qb, unsigned short* __restrict__ kb, unsigned short* __restrict__ vT)
{
    __shared__ unsigned short Wt[64][264];
    __shared__ unsigned short Xt[64][264];
    const int z  = blockIdx.z;
    const int m0 = blockIdx.x * 64;
    const int o0 = blockIdx.y * 64;
    const float* W = (z == 0) ? Wq : (z == 1 ? Wk : Wv);
    const int t = threadIdx.x;

#pragma unroll
    for (int i = 0; i < 16; ++i) {
        int fidx = i * 256 + t;
        int row = fidx >> 6, c4 = fidx & 63;
        f32x4 vW = *reinterpret_cast<const f32x4*>(W + (size_t)(o0 + row) * NH + c4 * 4);
        f32x4 vX = *reinterpret_cast<const f32x4*>(x + (size_t)(m0 + row) * NH + c4 * 4);
        u32x2 pw; pw[0] = pack2(vW[0], vW[1]); pw[1] = pack2(vW[2], vW[3]);
        u32x2 px; px[0] = pack2(vX[0], vX[1]); px[1] = pack2(vX[2], vX[3]);
        *reinterpret_cast<u32x2*>(&Wt[row][c4 * 4]) = pw;
        *reinterpret_cast<u32x2*>(&Xt[row][c4 * 4]) = px;
    }
    __syncthreads();

    const int w = t >> 6, lane = t & 63, lr = lane & 15, half = lane >> 4;
    const unsigned short (*Ab)[264] = (z < 2) ? Wt : Xt;
    const unsigned short (*Bb)[264] = (z < 2) ? Xt : Wt;
    const int ar0 = 32 * (w >> 1), br0 = 32 * (w & 1);

    f32x4 acc[2][2] = {};
#pragma unroll
    for (int kk = 0; kk < 8; ++kk) {
        bf16x8 a[2], bfr[2];
#pragma unroll
        for (int f = 0; f < 2; ++f) {
            a[f]   = *reinterpret_cast<const bf16x8*>(&Ab[ar0 + 16 * f + lr][32 * kk + 8 * half]);
            bfr[f] = *reinterpret_cast<const bf16x8*>(&Bb[br0 + 16 * f + lr][32 * kk + 8 * half]);
        }
#pragma unroll
        for (int fa = 0; fa < 2; ++fa)
#pragma unroll
            for (int fb = 0; fb < 2; ++fb)
                acc[fa][fb] = MFMA16(a[fa], bfr[fb], acc[fa][fb], 0, 0, 0);
    }

    if (z < 2) {
        unsigned short* dst = z ? kb : qb;
#pragma unroll
        for (int fa = 0; fa < 2; ++fa)
#pragma unroll
            for (int fb = 0; fb < 2; ++fb) {
                int m = m0 + br0 + 16 * fb + lr;
                int o = o0 + ar0 + 16 * fa + 4 * half;
                u32x2 pk; pk[0] = pack2(acc[fa][fb][0], acc[fa][fb][1]);
                pk[1] = pack2(acc[fa][fb][2], acc[fa][fb][3]);
                *reinterpret_cast<u32x2*>(dst + (size_t)m * NH + o) = pk;
            }
    } else {
#pragma unroll
        for (int fa = 0; fa < 2; ++fa)
#pragma unroll
            for (int fb = 0; fb < 2; ++fb) {
                int dg = m0 + ar0 + 16 * fa + 4 * half;
                int o  = o0 + br0 + 16 * fb + lr;
                int bb = dg >> 11, di = dg & 2047;
                u32x2 pk; pk[0] = pack2(acc[fa][fb][0], acc[fa][fb][1]);
                pk[1] = pack2(acc[fa][fb][2], acc[fa][fb][3]);
                *reinterpret_cast<u32x2*>(vT + ((size_t)bb * NH + o) * ND + di) = pk;
            }
    }
}

// ---------------------------------------------------------------------------
// Kernel 2: flash attention partials. 32-e tiles, double-buffered K/V in LDS,
// 72KB/block -> 2 blocks/CU (16 waves/CU). grid 512: b=bid&7 (XCD),
// eh=(bid>>3)&1 (e-half), qt=bid>>4. 8 waves: pair pr=w&3 owns 16 q-rows
// (QK+softmax duplicated in pair), side=w>>2 splits PV fo-half.
// ---------------------------------------------------------------------------
__global__ __launch_bounds__(512, 4) void attn_kernel(
    const unsigned short* __restrict__ qb, const unsigned short* __restrict__ kb,
    const unsigned short* __restrict__ vT, const int* __restrict__ adj,
    unsigned short* __restrict__ part, float* __restrict__ mpart, float* __restrict__ lpart)
{
    __shared__ unsigned char KT[2][16384];   // [32 e][512 B], swz (r&7)<<4
    __shared__ unsigned char VTl[2][16384];  // [256 o][64 B], swz ((o>>1)&3)<<4
    __shared__ unsigned char P[8][1024];     // per-wave [16 d][64 B], swz ((d>>1)&3)<<4

    const int bid = blockIdx.x;
    const int b = bid & 7, eh = (bid >> 3) & 1, qt = bid >> 4;
    const int t = threadIdx.x, w = t >> 6, lane = t & 63, lr = lane & 15, half = lane >> 4;
    const int pr = w & 3, side = w >> 2;
    const int qbase = qt * 64 + pr * 16;
    const int kswz = (lr & 7) << 4;
    const int vswz = ((lr >> 1) & 3) << 4;

    bf16x8 qf[8];
    const size_t qrow = ((size_t)b * ND + qbase + lr) * NH;
#pragma unroll
    for (int kk = 0; kk < 8; ++kk)
        qf[kk] = *reinterpret_cast<const bf16x8*>(qb + qrow + 32 * kk + 8 * half);

    const char* kbc = (const char*)kb + (size_t)b * ND * 512 + (size_t)eh * 1024 * 512;
    const char* vtc = (const char*)vT + (size_t)b * NH * ND * 2 + (size_t)eh * 1024 * 2;
    const int* adjr = adj + ((size_t)b * ND + qbase + lr) * ND + eh * 1024;

    auto stageK = [&](int buf, int e0s) {
#pragma unroll
        for (int i = 0; i < 2; ++i) {
            int off = i * 8192 + t * 16;
            int r = off >> 9;
            int c = off & 511;
            int src = c ^ ((r & 7) << 4);
            gload_lds16(kbc + (size_t)(e0s + r) * 512 + src, &KT[buf][off]);
        }
    };
    auto stageV = [&](int buf, int e0s) {
#pragma unroll
        for (int i = 0; i < 2; ++i) {
            int off = i * 8192 + t * 16;
            int o = off >> 6;
            int c = off & 63;
            int src = c ^ (((o >> 1) & 3) << 4);
            gload_lds16(vtc + (size_t)o * (ND * 2) + e0s * 2 + src, &VTl[buf][off]);
        }
    };

    f32x4 acc[8] = {};
    float m_run = -__builtin_inff(), l_run = 0.f;
    const float SC = 0.0625f, L2E = 1.44269504f;

    stageK(0, 0);
    stageV(0, 0);
    __syncthreads();

    for (int tt = 0; tt < 32; ++tt) {
        const int cur = tt & 1;
        if (tt < 31) {
            stageK(cur ^ 1, (tt + 1) * 32);
            stageV(cur ^ 1, (tt + 1) * 32);
        }
        i32x4 aj[2];
#pragma unroll
        for (int fe = 0; fe < 2; ++fe)
            aj[fe] = *reinterpret_cast<const i32x4*>(adjr + tt * 32 + fe * 16 + 4 * half);

        // ---- QK^T ----
        const char* Kc = (const char*)&KT[cur][0];
        f32x4 s[2] = {};
#pragma unroll
        for (int kk = 0; kk < 8; ++kk)
#pragma unroll
            for (int fe = 0; fe < 2; ++fe) {
                bf16x8 kf = *reinterpret_cast<const bf16x8*>(
                    Kc + (fe * 16 + lr) * 512 + ((kk * 64 + half * 16) ^ kswz));
                s[fe] = MFMA16(kf, qf[kk], s[fe], 0, 0, 0);
            }

        // ---- mask + online softmax (defer-max) ----
        float pv[2][4];
        float tmax = -__builtin_inff();
#pragma unroll
        for (int fe = 0; fe < 2; ++fe)
#pragma unroll
            for (int r = 0; r < 4; ++r) {
                float sv = s[fe][r] * SC;
                sv = (aj[fe][r] > 0) ? sv : -1e9f;
                pv[fe][r] = sv;
                tmax = fmaxf(tmax, sv);
            }
        tmax = fmaxf(tmax, __shfl_xor(tmax, 16));
        tmax = fmaxf(tmax, __shfl_xor(tmax, 32));

        if (!__all(tmax <= m_run + 8.0f)) {
            const float m_new = fmaxf(m_run, tmax);
            const float scale = exp2f((m_run - m_new) * L2E);
#pragma unroll
            for (int j = 0; j < 8; ++j)
#pragma unroll
                for (int r = 0; r < 4; ++r) acc[j][r] *= scale;
            l_run *= scale;
            m_run = m_new;
        }
        float psum = 0.f;
#pragma unroll
        for (int fe = 0; fe < 2; ++fe)
#pragma unroll
            for (int r = 0; r < 4; ++r) {
                float pe = exp2f((pv[fe][r] - m_run) * L2E);
                pv[fe][r] = pe;
                psum += pe;
            }
        psum += __shfl_xor(psum, 16);
        psum += __shfl_xor(psum, 32);
        l_run += psum;

        // ---- P -> per-wave swizzled LDS, read back as B-frag ----
        char* Pw = (char*)&P[w][0] + lr * 64;
        const int pswz = ((lr >> 1) & 3) << 4;
#pragma unroll
        for (int fe = 0; fe < 2; ++fe) {
            u32x2 pk; pk[0] = pack2(pv[fe][0], pv[fe][1]); pk[1] = pack2(pv[fe][2], pv[fe][3]);
            *reinterpret_cast<u32x2*>(Pw + ((fe * 32 + half * 8) ^ pswz)) = pk;
        }
        bf16x8 pf = *reinterpret_cast<const bf16x8*>(Pw + ((half * 16) ^ pswz));

        // ---- PV: this wave's fo-half ----
        const char* Vc = (const char*)&VTl[cur][0];
#pragma unroll
        for (int j = 0; j < 8; ++j) {
            const int o = (side * 8 + j) * 16 + lr;
            bf16x8 vf = *reinterpret_cast<const bf16x8*>(
                Vc + o * 64 + ((half * 16) ^ (((o >> 1) & 3) << 4)));
            acc[j] = MFMA16(vf, pf, acc[j], 0, 0, 0);
        }
        __syncthreads();
    }

    // ---- epilogue: unnormalized bf16 partials + m/l ----
    const int qg = b * ND + qbase + lr;
    const size_t pbase = ((size_t)eh * 16384 + qg) * 256;
#pragma unroll
    for (int j = 0; j < 8; ++j) {
        const int fo = side * 8 + j;
        u32x2 pk; pk[0] = pack2(acc[j][0], acc[j][1]);
        pk[1] = pack2(acc[j][2], acc[j][3]);
        *reinterpret_cast<u32x2*>(part + pbase + fo * 16 + 4 * half) = pk;
    }
    if (side == 0 && half == 0) {
        mpart[eh * 16384 + qg] = m_run;
        lpart[eh * 16384 + qg] = l_run;
    }
}

// ---------------------------------------------------------------------------
// Kernel 2b: combine the two e-half partials -> agg (bf16).
// ---------------------------------------------------------------------------
__global__ __launch_bounds__(256) void combine_kernel(
    const unsigned short* __restrict__ part, const float* __restrict__ mpart,
    const float* __restrict__ lpart, unsigned short* __restrict__ agg)
{
    const int t = threadIdx.x, w = t >> 6, lane = t & 63;
    const int q = blockIdx.x * 4 + w;
    const float L2E = 1.44269504f;
    const float m0 = mpart[q], m1 = mpart[16384 + q];
    const float l0 = lpart[q], l1 = lpart[16384 + q];
    const float mm = fmaxf(m0, m1);
    const float s0 = exp2f((m0 - mm) * L2E);
    const float s1 = exp2f((m1 - mm) * L2E);
    const float inv = 1.f / (s0 * l0 + s1 * l1);

    u32x2 a = *reinterpret_cast<const u32x2*>(part + (size_t)q * 256 + lane * 4);
    u32x2 c = *reinterpret_cast<const u32x2*>(part + (size_t)(16384 + q) * 256 + lane * 4);
    float av[4], cv[4];
    av[0] = __uint_as_float(a[0] << 16); av[1] = __uint_as_float(a[0] & 0xffff0000u);
    av[2] = __uint_as_float(a[1] << 16); av[3] = __uint_as_float(a[1] & 0xffff0000u);
    cv[0] = __uint_as_float(c[0] << 16); cv[1] = __uint_as_float(c[0] & 0xffff0000u);
    cv[2] = __uint_as_float(c[1] << 16); cv[3] = __uint_as_float(c[1] & 0xffff0000u);
    float o[4];
#pragma unroll
    for (int r = 0; r < 4; ++r) o[r] = (s0 * av[r] + s1 * cv[r]) * inv;
    u32x2 pk; pk[0] = pack2(o[0], o[1]); pk[1] = pack2(o[2], o[3]);
    *reinterpret_cast<u32x2*>(agg + (size_t)q * 256 + lane * 4) = pk;
}

// ---------------------------------------------------------------------------
// Kernel 3a: h = agg @ Wp^T + bp + x   (f32 out)
// ---------------------------------------------------------------------------
__global__ __launch_bounds__(256) void oproj_kernel(
    const unsigned short* __restrict__ agg, const float* __restrict__ Wp,
    const float* __restrict__ bp, const float* __restrict__ x, float* __restrict__ h)
{
    __shared__ unsigned short Wt[64][264];
    __shared__ unsigned short Xt[64][264];
    const int m0 = blockIdx.x * 64, p0 = blockIdx.y * 64;
    const int t = threadIdx.x;

#pragma unroll
    for (int i = 0; i < 16; ++i) {
        int fidx = i * 256 + t, row = fidx >> 6, c4 = fidx & 63;
        f32x4 vW = *reinterpret_cast<const f32x4*>(Wp + (size_t)(p0 + row) * NH + c4 * 4);
        u32x2 pw; pw[0] = pack2(vW[0], vW[1]); pw[1] = pack2(vW[2], vW[3]);
        *reinterpret_cast<u32x2*>(&Wt[row][c4 * 4]) = pw;
    }
#pragma unroll
    for (int i = 0; i < 8; ++i) {
        int fidx = i * 256 + t, row = fidx >> 5, c8 = fidx & 31;
        u32x4 vA = *reinterpret_cast<const u32x4*>(agg + (size_t)(m0 + row) * NH + c8 * 8);
        *reinterpret_cast<u32x4*>(&Xt[row][c8 * 8]) = vA;
    }
    __syncthreads();

    const int w = t >> 6, lane = t & 63, lr = lane & 15, half = lane >> 4;
    const int ar0 = 32 * (w >> 1), br0 = 32 * (w & 1);

    f32x4 acc[2][2] = {};
#pragma unroll
    for (int kk = 0; kk < 8; ++kk) {
        bf16x8 a[2], bfr[2];
#pragma unroll
        for (int f = 0; f < 2; ++f) {
            a[f]   = *reinterpret_cast<const bf16x8*>(&Wt[ar0 + 16 * f + lr][32 * kk + 8 * half]);
            bfr[f] = *reinterpret_cast<const bf16x8*>(&Xt[br0 + 16 * f + lr][32 * kk + 8 * half]);
        }
#pragma unroll
        for (int fa = 0; fa < 2; ++fa)
#pragma unroll
            for (int fb = 0; fb < 2; ++fb)
                acc[fa][fb] = MFMA16(a[fa], bfr[fb], acc[fa][fb], 0, 0, 0);
    }

#pragma unroll
    for (int fa = 0; fa < 2; ++fa)
#pragma unroll
        for (int fb = 0; fb < 2; ++fb) {
            int pcol = p0 + ar0 + 16 * fa + 4 * half;
            int m = m0 + br0 + 16 * fb + lr;
            f32x4 bias = *reinterpret_cast<const f32x4*>(bp + pcol);
            f32x4 xr   = *reinterpret_cast<const f32x4*>(x + (size_t)m * NH + pcol);
            f32x4 out;
#pragma unroll
            for (int r = 0; r < 4; ++r) out[r] = acc[fa][fb][r] + bias[r] + xr[r];
            *reinterpret_cast<f32x4*>(h + (size_t)m * NH + pcol) = out;
        }
}

// ---------------------------------------------------------------------------
// Kernel 3b: LayerNorm rows of h -> out.
// ---------------------------------------------------------------------------
__global__ __launch_bounds__(256) void ln_kernel(
    const float* __restrict__ h, const float* __restrict__ gamma,
    const float* __restrict__ beta, float* __restrict__ out)
{
    const int t = threadIdx.x, w = t >> 6, lane = t & 63;
    const size_t row = (size_t)blockIdx.x * 4 + w;
    const float* hr = h + row * NH;
    f32x4 v = *reinterpret_cast<const f32x4*>(hr + lane * 4);
    float s = v[0] + v[1] + v[2] + v[3];
#pragma unroll
    for (int off = 1; off < 64; off <<= 1) s += __shfl_xor(s, off);
    const float mu = s * (1.f / 256.f);
    f32x4 dv; float q = 0.f;
#pragma unroll
    for (int r = 0; r < 4; ++r) { dv[r] = v[r] - mu; q += dv[r] * dv[r]; }
#pragma unroll
    for (int off = 1; off < 64; off <<= 1) q += __shfl_xor(q, off);
    const float rs = rsqrtf(q * (1.f / 256.f) + 1e-5f);
    f32x4 g  = *reinterpret_cast<const f32x4*>(gamma + lane * 4);
    f32x4 be = *reinterpret_cast<const f32x4*>(beta + lane * 4);
    f32x4 o;
#pragma unroll
    for (int r = 0; r < 4; ++r) o[r] = dv[r] * rs * g[r] + be[r];
    *reinterpret_cast<f32x4*>(out + row * NH + lane * 4) = o;
}

extern "C" void kernel_launch(void* const* d_in, const int* in_sizes, int n_in,
                              void* d_out, int out_size, void* d_ws, size_t ws_size,
                              hipStream_t stream)
{
    const float* x     = (const float*)d_in[0];
    const int*   adj   = (const int*)d_in[1];
    const float* Wq    = (const float*)d_in[2];
    const float* Wk    = (const float*)d_in[3];
    const float* Wv    = (const float*)d_in[4];
    const float* Wp    = (const float*)d_in[5];
    const float* bp    = (const float*)d_in[6];
    const float* gamma = (const float*)d_in[7];
    const float* beta  = (const float*)d_in[8];

    char* ws = (char*)d_ws;
    const size_t MB = 1024 * 1024;
    unsigned short* qb    = (unsigned short*)(ws);
    unsigned short* kb    = (unsigned short*)(ws + 8 * MB);
    unsigned short* vT    = (unsigned short*)(ws + 16 * MB);
    unsigned short* agg   = qb;
    unsigned short* partb = (unsigned short*)(ws + 24 * MB);
    float* mpart = (float*)(ws + 40 * MB);
    float* lpart = (float*)(ws + 40 * MB + 128 * 1024);
    float* h = (float*)(ws + 8 * MB);
    float* out = (float*)d_out;

    qkv_kernel<<<dim3(256, 4, 3), 256, 0, stream>>>(x, Wq, Wk, Wv, qb, kb, vT);
    attn_kernel<<<dim3(512), 512, 0, stream>>>(qb, kb, vT, adj, partb, mpart, lpart);
    combine_kernel<<<dim3(4096), 256, 0, stream>>>(partb, mpart, lpart, agg);
    oproj_kernel<<<dim3(256, 4), 256, 0, stream>>>(agg, Wp, bp, x, h);
    ln_kernel<<<dim3(4096), 256, 0, stream>>>(h, gamma, beta, out);
}

// Round 6
// 122.461 us; speedup vs baseline: 1.3047x; 1.2233x over previous
//
#include <hip/hip_runtime.h>
#include <stdint.h>

#define NB 8
#define ND 2048
#define NH 256

typedef __attribute__((ext_vector_type(8))) short bf16x8;
typedef __attribute__((ext_vector_type(4))) float f32x4;
typedef __attribute__((ext_vector_type(16))) float f32x16;
typedef __attribute__((ext_vector_type(4))) int   i32x4;
typedef __attribute__((ext_vector_type(2))) unsigned int u32x2;
typedef __attribute__((ext_vector_type(4))) unsigned int u32x4;

#define MFMA16 __builtin_amdgcn_mfma_f32_16x16x32_bf16
#define MFMA32 __builtin_amdgcn_mfma_f32_32x32x16_bf16

__device__ __forceinline__ unsigned short f2bf(float f) {
    union { float f; unsigned int u; } c; c.f = f;
    unsigned int u = c.u + 0x7FFFu + ((c.u >> 16) & 1u);
    return (unsigned short)(u >> 16);
}
__device__ __forceinline__ unsigned int pack2(float a, float b) {
    return (unsigned int)f2bf(a) | ((unsigned int)f2bf(b) << 16);
}
__device__ __forceinline__ unsigned int cvtpk(float a, float b) {
    unsigned int r;
    asm("v_cvt_pk_bf16_f32 %0, %1, %2" : "=v"(r) : "v"(a), "v"(b));
    return r;
}
__device__ __forceinline__ void plswap(unsigned int& a, unsigned int& b) {
    asm volatile("v_permlane32_swap_b32 %0, %1" : "+v"(a), "+v"(b));
}
__device__ __forceinline__ bf16x8 mk8(unsigned int a, unsigned int b, unsigned int c, unsigned int d) {
    union { unsigned int u[4]; bf16x8 v; } x;
    x.u[0] = a; x.u[1] = b; x.u[2] = c; x.u[3] = d;
    return x.v;
}
__device__ __forceinline__ void gload_lds16(const void* g, void* l) {
    __builtin_amdgcn_global_load_lds(
        (const __attribute__((address_space(1))) void*)g,
        (__attribute__((address_space(3))) void*)l, 16, 0, 0);
}

// ---------------------------------------------------------------------------
// Kernel 1: q = x@Wq^T (row-major), k,v with attn-friendly layouts:
//   kb[b][koct 32][e 2048][8]  (K k-octet-major: contiguous per-MFMA A-frags)
//   vT[b][eoct 256][o 256][8]  (V e-octet-major)
// ---------------------------------------------------------------------------
__global__ __launch_bounds__(256) void qkv_kernel(
    const float* __restrict__ x,
    const float* __restrict__ Wq, const float* __restrict__ Wk, const float* __restrict__ Wv,
    unsigned short* __restrict__ qb, unsigned short* __restrict__ kb, unsigned short* __restrict__ vT)
{
    __shared__ unsigned short Wt[64][264];
    __shared__ unsigned short Xt[64][264];
    const int z  = blockIdx.z;
    const int m0 = blockIdx.x * 64;
    const int o0 = blockIdx.y * 64;
    const float* W = (z == 0) ? Wq : (z == 1 ? Wk : Wv);
    const int t = threadIdx.x;

#pragma unroll
    for (int i = 0; i < 16; ++i) {
        int fidx = i * 256 + t;
        int row = fidx >> 6, c4 = fidx & 63;
        f32x4 vW = *reinterpret_cast<const f32x4*>(W + (size_t)(o0 + row) * NH + c4 * 4);
        f32x4 vX = *reinterpret_cast<const f32x4*>(x + (size_t)(m0 + row) * NH + c4 * 4);
        u32x2 pw; pw[0] = pack2(vW[0], vW[1]); pw[1] = pack2(vW[2], vW[3]);
        u32x2 px; px[0] = pack2(vX[0], vX[1]); px[1] = pack2(vX[2], vX[3]);
        *reinterpret_cast<u32x2*>(&Wt[row][c4 * 4]) = pw;
        *reinterpret_cast<u32x2*>(&Xt[row][c4 * 4]) = px;
    }
    __syncthreads();

    const int w = t >> 6, lane = t & 63, lr = lane & 15, half = lane >> 4;
    const unsigned short (*Ab)[264] = (z == 2) ? Xt : Wt;
    const unsigned short (*Bb)[264] = (z == 2) ? Wt : Xt;
    const int ar0 = 32 * (w >> 1), br0 = 32 * (w & 1);

    f32x4 acc[2][2] = {};
#pragma unroll
    for (int kk = 0; kk < 8; ++kk) {
        bf16x8 a[2], bfr[2];
#pragma unroll
        for (int f = 0; f < 2; ++f) {
            a[f]   = *reinterpret_cast<const bf16x8*>(&Ab[ar0 + 16 * f + lr][32 * kk + 8 * half]);
            bfr[f] = *reinterpret_cast<const bf16x8*>(&Bb[br0 + 16 * f + lr][32 * kk + 8 * half]);
        }
#pragma unroll
        for (int fa = 0; fa < 2; ++fa)
#pragma unroll
            for (int fb = 0; fb < 2; ++fb)
                acc[fa][fb] = MFMA16(a[fa], bfr[fb], acc[fa][fb], 0, 0, 0);
    }

    if (z == 0) {
#pragma unroll
        for (int fa = 0; fa < 2; ++fa)
#pragma unroll
            for (int fb = 0; fb < 2; ++fb) {
                int m = m0 + br0 + 16 * fb + lr;
                int o = o0 + ar0 + 16 * fa + 4 * half;
                u32x2 pk; pk[0] = pack2(acc[fa][fb][0], acc[fa][fb][1]);
                pk[1] = pack2(acc[fa][fb][2], acc[fa][fb][3]);
                *reinterpret_cast<u32x2*>(qb + (size_t)m * NH + o) = pk;
            }
    } else if (z == 1) {
#pragma unroll
        for (int fa = 0; fa < 2; ++fa)
#pragma unroll
            for (int fb = 0; fb < 2; ++fb) {
                int m = m0 + br0 + 16 * fb + lr;          // token e
                int o = o0 + ar0 + 16 * fa + 4 * half;    // k-feature
                int bb = m >> 11, el = m & 2047;
                u32x2 pk; pk[0] = pack2(acc[fa][fb][0], acc[fa][fb][1]);
                pk[1] = pack2(acc[fa][fb][2], acc[fa][fb][3]);
                size_t idx = (((size_t)bb * 32 + (o >> 3)) * 2048 + el) * 8 + (o & 7);
                *reinterpret_cast<u32x2*>(kb + idx) = pk;
            }
    } else {
#pragma unroll
        for (int fa = 0; fa < 2; ++fa)
#pragma unroll
            for (int fb = 0; fb < 2; ++fb) {
                int dg = m0 + ar0 + 16 * fa + 4 * half;   // token e (4 consec)
                int o  = o0 + br0 + 16 * fb + lr;         // out feature
                int bb = dg >> 11, el = dg & 2047;
                u32x2 pk; pk[0] = pack2(acc[fa][fb][0], acc[fa][fb][1]);
                pk[1] = pack2(acc[fa][fb][2], acc[fa][fb][3]);
                size_t idx = (((size_t)bb * 256 + (el >> 3)) * 256 + o) * 8 + (el & 7);
                *reinterpret_cast<u32x2*>(vT + idx) = pk;
            }
    }
}

// ---------------------------------------------------------------------------
// Kernel 2: flash attention partials, 32x32x16 MFMA, in-register P.
// Wave owns 32 q-rows (lane&31 = its q-row = S^T column). K/V staged to LDS
// in per-MFMA-contiguous layouts (zero bank conflicts). One barrier per tile.
// ESP = e-splits (partials combined later), SIDES = o-split within block.
// ---------------------------------------------------------------------------
template<int ESP, int SIDES>
__global__ __launch_bounds__(512, 2) void attn_kernel(
    const unsigned short* __restrict__ qb, const unsigned short* __restrict__ kb,
    const unsigned short* __restrict__ vT, const int* __restrict__ adj,
    unsigned short* __restrict__ part, float* __restrict__ mpart, float* __restrict__ lpart)
{
    constexpr int GROUPS = 8 / SIDES;       // q-groups per block
    constexpr int QB = 32 * GROUPS;         // q-rows per block
    constexpr int NOT = 8 / SIDES;          // 32-o tiles per wave
    constexpr int NT = (ND / ESP) / 32;     // 32-e tiles per block
    constexpr int QTSH = (ESP == 4) ? 5 : 4;

    __shared__ unsigned char KT[2][16384];   // [koct 32][e 32][16B]
    __shared__ unsigned char VTl[2][16384];  // [eoct 4][o 256][16B]

    const int bid = blockIdx.x;
    const int b = bid & 7, es = (bid >> 3) & (ESP - 1), qt = bid >> QTSH;
    const int t = threadIdx.x, w = t >> 6, l = t & 63;
    const int lo32 = l & 31, hi = l >> 5;
    const int g = w & (GROUPS - 1), side = w / GROUPS;
    const int qbase = qt * QB + g * 32;
    const int obase = side * (256 / SIDES);
    const int ebase = es * (ND / ESP);
    const float SC = 0.0625f, L2E = 1.44269504f;

    // Q B-frags: lane holds col d = qbase+lo32, k-octet by hi
    bf16x8 qf[16];
    {
        const unsigned short* qr = qb + ((size_t)b * ND + qbase + lo32) * NH + 8 * hi;
#pragma unroll
        for (int kk = 0; kk < 16; ++kk)
            qf[kk] = *reinterpret_cast<const bf16x8*>(qr + kk * 16);
    }

    const char* kbc = (const char*)kb + ((size_t)b << 20);
    const char* vtc = (const char*)vT + ((size_t)b << 20);
    const int* adjr = adj + ((size_t)b * ND + qbase + lo32) * ND + ebase;

    auto stageK = [&](int buf, int tt) {
        const int e0s = ebase + tt * 32;
#pragma unroll
        for (int i = 0; i < 2; ++i) {
            int off = i * 8192 + t * 16;
            int koct = off >> 9, e = (off >> 4) & 31;
            gload_lds16(kbc + (size_t)koct * 32768 + (size_t)(e0s + e) * 16, &KT[buf][off]);
        }
    };
    auto stageV = [&](int buf, int tt) {
        const int Eb = (ebase + tt * 32) >> 3;
#pragma unroll
        for (int i = 0; i < 2; ++i) {
            int off = i * 8192 + t * 16;
            int eoct = off >> 12, o = (off >> 4) & 255;
            gload_lds16(vtc + (size_t)(Eb + eoct) * 4096 + (size_t)o * 16, &VTl[buf][off]);
        }
    };

    f32x16 acc[NOT] = {};
    float m_run = -__builtin_inff(), l_run = 0.f;

    stageK(0, 0); stageV(0, 0);
    __syncthreads();

    for (int tt = 0; tt < NT; ++tt) {
        const int cur = tt & 1;
        if (tt < NT - 1) { stageK(cur ^ 1, tt + 1); stageV(cur ^ 1, tt + 1); }

        i32x4 aj[4];
#pragma unroll
        for (int gg = 0; gg < 4; ++gg)
            aj[gg] = *reinterpret_cast<const i32x4*>(adjr + tt * 32 + gg * 8 + 4 * hi);

        // ---- QK^T: S^T[e 32][d 32], A = K rows (contiguous 1KB reads) ----
        const char* Kc = (const char*)&KT[cur][0];
        f32x16 s = {};
#pragma unroll
        for (int kk = 0; kk < 16; ++kk) {
            bf16x8 kf = *reinterpret_cast<const bf16x8*>(Kc + kk * 1024 + hi * 512 + lo32 * 16);
            s = MFMA32(kf, qf[kk], s, 0, 0, 0);
        }

        // ---- mask + online softmax (per-lane d; one shfl to merge halves) ----
        float p[16];
        float tmax = -__builtin_inff();
#pragma unroll
        for (int gg = 0; gg < 4; ++gg)
#pragma unroll
            for (int r = 0; r < 4; ++r) {
                float sv = s[gg * 4 + r] * SC;
                sv = (aj[gg][r] > 0) ? sv : -1e9f;
                p[gg * 4 + r] = sv;
                tmax = fmaxf(tmax, sv);
            }
        tmax = fmaxf(tmax, __shfl_xor(tmax, 32));
        if (!__all(tmax <= m_run + 8.0f)) {
            const float m_new = fmaxf(m_run, tmax);
            const float scale = exp2f((m_run - m_new) * L2E);
#pragma unroll
            for (int ot = 0; ot < NOT; ++ot)
#pragma unroll
                for (int r = 0; r < 16; ++r) acc[ot][r] *= scale;
            l_run *= scale;
            m_run = m_new;
        }
        float psum = 0.f;
#pragma unroll
        for (int r2 = 0; r2 < 16; ++r2) {
            float pe = exp2f((p[r2] - m_run) * L2E);
            p[r2] = pe;
            psum += pe;
        }
        psum += __shfl_xor(psum, 32);
        l_run += psum;

        // ---- P -> B-frags fully in-register (cvt_pk + permlane32_swap) ----
        unsigned int c0 = cvtpk(p[0], p[1]),   c1 = cvtpk(p[2], p[3]);
        unsigned int c2 = cvtpk(p[4], p[5]),   c3 = cvtpk(p[6], p[7]);
        plswap(c0, c2); plswap(c1, c3);
        unsigned int c4 = cvtpk(p[8], p[9]),   c5 = cvtpk(p[10], p[11]);
        unsigned int c6 = cvtpk(p[12], p[13]), c7 = cvtpk(p[14], p[15]);
        plswap(c4, c6); plswap(c5, c7);
        const bf16x8 pf0 = mk8(c0, c1, c2, c3);
        const bf16x8 pf1 = mk8(c4, c5, c6, c7);

        // ---- PV: A = V rows (contiguous 1KB reads), acc[o-tile] ----
        const char* Vc = (const char*)&VTl[cur][0];
#pragma unroll
        for (int ot = 0; ot < NOT; ++ot) {
            bf16x8 vf = *reinterpret_cast<const bf16x8*>(
                Vc + hi * 4096 + (size_t)(obase + ot * 32 + lo32) * 16);
            acc[ot] = MFMA32(vf, pf0, acc[ot], 0, 0, 0);
        }
#pragma unroll
        for (int ot = 0; ot < NOT; ++ot) {
            bf16x8 vf = *reinterpret_cast<const bf16x8*>(
                Vc + 8192 + hi * 4096 + (size_t)(obase + ot * 32 + lo32) * 16);
            acc[ot] = MFMA32(vf, pf1, acc[ot], 0, 0, 0);
        }
        __syncthreads();
    }

    // ---- epilogue: unnormalized bf16 partials + m/l ----
    const int qg = b * ND + qbase + lo32;
    unsigned short* pb = part + ((size_t)es * 16384 + qg) * 256;
#pragma unroll
    for (int ot = 0; ot < NOT; ++ot)
#pragma unroll
        for (int g2 = 0; g2 < 4; ++g2) {
            u32x2 pk;
            pk[0] = pack2(acc[ot][g2 * 4 + 0], acc[ot][g2 * 4 + 1]);
            pk[1] = pack2(acc[ot][g2 * 4 + 2], acc[ot][g2 * 4 + 3]);
            *reinterpret_cast<u32x2*>(pb + obase + ot * 32 + g2 * 8 + 4 * hi) = pk;
        }
    if (hi == 0 && side == 0) {
        mpart[(size_t)es * 16384 + qg] = m_run;
        lpart[(size_t)es * 16384 + qg] = l_run;
    }
}

// ---------------------------------------------------------------------------
// Kernel 2b: combine ESP e-split partials -> agg (bf16). 8 rows/block.
// ---------------------------------------------------------------------------
template<int ESP>
__global__ __launch_bounds__(256) void combine_kernel(
    const unsigned short* __restrict__ part, const float* __restrict__ mpart,
    const float* __restrict__ lpart, unsigned short* __restrict__ agg)
{
    const float L2E = 1.44269504f;
    const int t = threadIdx.x;
    const int row8 = t >> 5, cw = t & 31;
    const int q = blockIdx.x * 8 + row8;

    float me[ESP], le[ESP], M = -__builtin_inff();
#pragma unroll
    for (int e = 0; e < ESP; ++e) {
        me[e] = mpart[(size_t)e * 16384 + q];
        le[e] = lpart[(size_t)e * 16384 + q];
        M = fmaxf(M, me[e]);
    }
    float wsum = 0.f;
#pragma unroll
    for (int e = 0; e < ESP; ++e) { me[e] = exp2f((me[e] - M) * L2E); wsum += me[e] * le[e]; }
    const float inv = 1.f / wsum;

    float o[8] = {};
#pragma unroll
    for (int e = 0; e < ESP; ++e) {
        u32x4 v = *reinterpret_cast<const u32x4*>(part + ((size_t)e * 16384 + q) * 256 + cw * 8);
        const float ce = me[e] * inv;
#pragma unroll
        for (int j = 0; j < 4; ++j) {
            o[2 * j]     += ce * __uint_as_float(v[j] << 16);
            o[2 * j + 1] += ce * __uint_as_float(v[j] & 0xffff0000u);
        }
    }
    u32x4 pk;
#pragma unroll
    for (int j = 0; j < 4; ++j) pk[j] = pack2(o[2 * j], o[2 * j + 1]);
    *reinterpret_cast<u32x4*>(agg + (size_t)q * 256 + cw * 8) = pk;
}

// ---------------------------------------------------------------------------
// Kernel 3a: h = agg @ Wp^T + bp + x   (f32 out)
// ---------------------------------------------------------------------------
__global__ __launch_bounds__(256) void oproj_kernel(
    const unsigned short* __restrict__ agg, const float* __restrict__ Wp,
    const float* __restrict__ bp, const float* __restrict__ x, float* __restrict__ h)
{
    __shared__ unsigned short Wt[64][264];
    __shared__ unsigned short Xt[64][264];
    const int m0 = blockIdx.x * 64, p0 = blockIdx.y * 64;
    const int t = threadIdx.x;

#pragma unroll
    for (int i = 0; i < 16; ++i) {
        int fidx = i * 256 + t, row = fidx >> 6, c4 = fidx & 63;
        f32x4 vW = *reinterpret_cast<const f32x4*>(Wp + (size_t)(p0 + row) * NH + c4 * 4);
        u32x2 pw; pw[0] = pack2(vW[0], vW[1]); pw[1] = pack2(vW[2], vW[3]);
        *reinterpret_cast<u32x2*>(&Wt[row][c4 * 4]) = pw;
    }
#pragma unroll
    for (int i = 0; i < 8; ++i) {
        int fidx = i * 256 + t, row = fidx >> 5, c8 = fidx & 31;
        u32x4 vA = *reinterpret_cast<const u32x4*>(agg + (size_t)(m0 + row) * NH + c8 * 8);
        *reinterpret_cast<u32x4*>(&Xt[row][c8 * 8]) = vA;
    }
    __syncthreads();

    const int w = t >> 6, lane = t & 63, lr = lane & 15, half = lane >> 4;
    const int ar0 = 32 * (w >> 1), br0 = 32 * (w & 1);

    f32x4 acc[2][2] = {};
#pragma unroll
    for (int kk = 0; kk < 8; ++kk) {
        bf16x8 a[2], bfr[2];
#pragma unroll
        for (int f = 0; f < 2; ++f) {
            a[f]   = *reinterpret_cast<const bf16x8*>(&Wt[ar0 + 16 * f + lr][32 * kk + 8 * half]);
            bfr[f] = *reinterpret_cast<const bf16x8*>(&Xt[br0 + 16 * f + lr][32 * kk + 8 * half]);
        }
#pragma unroll
        for (int fa = 0; fa < 2; ++fa)
#pragma unroll
            for (int fb = 0; fb < 2; ++fb)
                acc[fa][fb] = MFMA16(a[fa], bfr[fb], acc[fa][fb], 0, 0, 0);
    }

#pragma unroll
    for (int fa = 0; fa < 2; ++fa)
#pragma unroll
        for (int fb = 0; fb < 2; ++fb) {
            int pcol = p0 + ar0 + 16 * fa + 4 * half;
            int m = m0 + br0 + 16 * fb + lr;
            f32x4 bias = *reinterpret_cast<const f32x4*>(bp + pcol);
            f32x4 xr   = *reinterpret_cast<const f32x4*>(x + (size_t)m * NH + pcol);
            f32x4 out;
#pragma unroll
            for (int r = 0; r < 4; ++r) out[r] = acc[fa][fb][r] + bias[r] + xr[r];
            *reinterpret_cast<f32x4*>(h + (size_t)m * NH + pcol) = out;
        }
}

// ---------------------------------------------------------------------------
// Kernel 3b: LayerNorm rows of h -> out.
// ---------------------------------------------------------------------------
__global__ __launch_bounds__(256) void ln_kernel(
    const float* __restrict__ h, const float* __restrict__ gamma,
    const float* __restrict__ beta, float* __restrict__ out)
{
    const int t = threadIdx.x, w = t >> 6, lane = t & 63;
    const size_t row = (size_t)blockIdx.x * 4 + w;
    const float* hr = h + row * NH;
    f32x4 v = *reinterpret_cast<const f32x4*>(hr + lane * 4);
    float s = v[0] + v[1] + v[2] + v[3];
#pragma unroll
    for (int off = 1; off < 64; off <<= 1) s += __shfl_xor(s, off);
    const float mu = s * (1.f / 256.f);
    f32x4 dv; float q = 0.f;
#pragma unroll
    for (int r = 0; r < 4; ++r) { dv[r] = v[r] - mu; q += dv[r] * dv[r]; }
#pragma unroll
    for (int off = 1; off < 64; off <<= 1) q += __shfl_xor(q, off);
    const float rs = rsqrtf(q * (1.f / 256.f) + 1e-5f);
    f32x4 g  = *reinterpret_cast<const f32x4*>(gamma + lane * 4);
    f32x4 be = *reinterpret_cast<const f32x4*>(beta + lane * 4);
    f32x4 o;
#pragma unroll
    for (int r = 0; r < 4; ++r) o[r] = dv[r] * rs * g[r] + be[r];
    *reinterpret_cast<f32x4*>(out + row * NH + lane * 4) = o;
}

extern "C" void kernel_launch(void* const* d_in, const int* in_sizes, int n_in,
                              void* d_out, int out_size, void* d_ws, size_t ws_size,
                              hipStream_t stream)
{
    const float* x     = (const float*)d_in[0];
    const int*   adj   = (const int*)d_in[1];
    const float* Wq    = (const float*)d_in[2];
    const float* Wk    = (const float*)d_in[3];
    const float* Wv    = (const float*)d_in[4];
    const float* Wp    = (const float*)d_in[5];
    const float* bp    = (const float*)d_in[6];
    const float* gamma = (const float*)d_in[7];
    const float* beta  = (const float*)d_in[8];

    char* ws = (char*)d_ws;
    const size_t MB = 1024 * 1024;
    unsigned short* qb    = (unsigned short*)(ws);
    unsigned short* kb    = (unsigned short*)(ws + 8 * MB);
    unsigned short* vT    = (unsigned short*)(ws + 16 * MB);
    unsigned short* agg   = qb;
    unsigned short* partb = (unsigned short*)(ws + 24 * MB);
    float* h = (float*)(ws + 8 * MB);
    float* out = (float*)d_out;

    qkv_kernel<<<dim3(256, 4, 3), 256, 0, stream>>>(x, Wq, Wk, Wv, qb, kb, vT);

    const bool big = ws_size >= (size_t)57 * MB;
    if (big) {
        float* mpart = (float*)(ws + 56 * MB);
        float* lpart = (float*)(ws + 56 * MB + 256 * 1024);
        attn_kernel<4, 1><<<dim3(256), 512, 0, stream>>>(qb, kb, vT, adj, partb, mpart, lpart);
        combine_kernel<4><<<dim3(2048), 256, 0, stream>>>(partb, mpart, lpart, agg);
    } else {
        float* mpart = (float*)(ws + 40 * MB);
        float* lpart = (float*)(ws + 40 * MB + 128 * 1024);
        attn_kernel<2, 2><<<dim3(256), 512, 0, stream>>>(qb, kb, vT, adj, partb, mpart, lpart);
        combine_kernel<2><<<dim3(2048), 256, 0, stream>>>(partb, mpart, lpart, agg);
    }

    oproj_kernel<<<dim3(256, 4), 256, 0, stream>>>(agg, Wp, bp, x, h);
    ln_kernel<<<dim3(4096), 256, 0, stream>>>(h, gamma, beta, out);
}

// Round 7
// 118.508 us; speedup vs baseline: 1.3482x; 1.0334x over previous
//
#include <hip/hip_runtime.h>
#include <stdint.h>

#define NB 8
#define ND 2048
#define NH 256

typedef __attribute__((ext_vector_type(8))) short bf16x8;
typedef __attribute__((ext_vector_type(4))) float f32x4;
typedef __attribute__((ext_vector_type(16))) float f32x16;
typedef __attribute__((ext_vector_type(4))) int   i32x4;
typedef __attribute__((ext_vector_type(2))) unsigned int u32x2;
typedef __attribute__((ext_vector_type(4))) unsigned int u32x4;

#define MFMA16 __builtin_amdgcn_mfma_f32_16x16x32_bf16
#define MFMA32 __builtin_amdgcn_mfma_f32_32x32x16_bf16

__device__ __forceinline__ unsigned short f2bf(float f) {
    union { float f; unsigned int u; } c; c.f = f;
    unsigned int u = c.u + 0x7FFFu + ((c.u >> 16) & 1u);
    return (unsigned short)(u >> 16);
}
__device__ __forceinline__ unsigned int pack2(float a, float b) {
    return (unsigned int)f2bf(a) | ((unsigned int)f2bf(b) << 16);
}
__device__ __forceinline__ unsigned int cvtpk(float a, float b) {
    unsigned int r;
    asm("v_cvt_pk_bf16_f32 %0, %1, %2" : "=v"(r) : "v"(a), "v"(b));
    return r;
}
__device__ __forceinline__ void plswap(unsigned int& a, unsigned int& b) {
    asm volatile("v_permlane32_swap_b32 %0, %1" : "+v"(a), "+v"(b));
}
__device__ __forceinline__ bf16x8 mk8(unsigned int a, unsigned int b, unsigned int c, unsigned int d) {
    union { unsigned int u[4]; bf16x8 v; } x;
    x.u[0] = a; x.u[1] = b; x.u[2] = c; x.u[3] = d;
    return x.v;
}
__device__ __forceinline__ void gload_lds16(const void* g, void* l) {
    __builtin_amdgcn_global_load_lds(
        (const __attribute__((address_space(1))) void*)g,
        (__attribute__((address_space(3))) void*)l, 16, 0, 0);
}
__device__ __forceinline__ float bflo(unsigned int u) { return __uint_as_float(u << 16); }
__device__ __forceinline__ float bfhi(unsigned int u) { return __uint_as_float(u & 0xffff0000u); }

// ---------------------------------------------------------------------------
// Kernel 1 (merged z): block (m0,o0) stages x-tile ONCE, loops Wq/Wk/Wv.
//   q row-major; kb[b][koct 32][e 2048][8]; vT[b][eoct 256][o 256][8]
// ---------------------------------------------------------------------------
__global__ __launch_bounds__(256) void qkv_kernel(
    const float* __restrict__ x,
    const float* __restrict__ Wq, const float* __restrict__ Wk, const float* __restrict__ Wv,
    unsigned short* __restrict__ qb, unsigned short* __restrict__ kb, unsigned short* __restrict__ vT)
{
    __shared__ unsigned short Wt[64][264];
    __shared__ unsigned short Xt[64][264];
    const int m0 = blockIdx.x * 64;
    const int o0 = blockIdx.y * 64;
    const int t = threadIdx.x;
    const int w = t >> 6, lane = t & 63, lr = lane & 15, half = lane >> 4;
    const int ar0 = 32 * (w >> 1), br0 = 32 * (w & 1);

    // initial stage: x tile + Wq tile
#pragma unroll
    for (int i = 0; i < 16; ++i) {
        int fidx = i * 256 + t, row = fidx >> 6, c4 = fidx & 63;
        f32x4 vW = *reinterpret_cast<const f32x4*>(Wq + (size_t)(o0 + row) * NH + c4 * 4);
        f32x4 vX = *reinterpret_cast<const f32x4*>(x + (size_t)(m0 + row) * NH + c4 * 4);
        u32x2 pw; pw[0] = pack2(vW[0], vW[1]); pw[1] = pack2(vW[2], vW[3]);
        u32x2 px; px[0] = pack2(vX[0], vX[1]); px[1] = pack2(vX[2], vX[3]);
        *reinterpret_cast<u32x2*>(&Wt[row][c4 * 4]) = pw;
        *reinterpret_cast<u32x2*>(&Xt[row][c4 * 4]) = px;
    }
    __syncthreads();

    for (int z = 0; z < 3; ++z) {
        const unsigned short (*Ab)[264] = (z == 2) ? Xt : Wt;
        const unsigned short (*Bb)[264] = (z == 2) ? Wt : Xt;

        f32x4 acc[2][2] = {};
#pragma unroll
        for (int kk = 0; kk < 8; ++kk) {
            bf16x8 a[2], bfr[2];
#pragma unroll
            for (int f = 0; f < 2; ++f) {
                a[f]   = *reinterpret_cast<const bf16x8*>(&Ab[ar0 + 16 * f + lr][32 * kk + 8 * half]);
                bfr[f] = *reinterpret_cast<const bf16x8*>(&Bb[br0 + 16 * f + lr][32 * kk + 8 * half]);
            }
#pragma unroll
            for (int fa = 0; fa < 2; ++fa)
#pragma unroll
                for (int fb = 0; fb < 2; ++fb)
                    acc[fa][fb] = MFMA16(a[fa], bfr[fb], acc[fa][fb], 0, 0, 0);
        }

        if (z == 0) {
#pragma unroll
            for (int fa = 0; fa < 2; ++fa)
#pragma unroll
                for (int fb = 0; fb < 2; ++fb) {
                    int m = m0 + br0 + 16 * fb + lr;
                    int o = o0 + ar0 + 16 * fa + 4 * half;
                    u32x2 pk; pk[0] = pack2(acc[fa][fb][0], acc[fa][fb][1]);
                    pk[1] = pack2(acc[fa][fb][2], acc[fa][fb][3]);
                    *reinterpret_cast<u32x2*>(qb + (size_t)m * NH + o) = pk;
                }
        } else if (z == 1) {
#pragma unroll
            for (int fa = 0; fa < 2; ++fa)
#pragma unroll
                for (int fb = 0; fb < 2; ++fb) {
                    int m = m0 + br0 + 16 * fb + lr;          // token e
                    int o = o0 + ar0 + 16 * fa + 4 * half;    // k-feature
                    int bb = m >> 11, el = m & 2047;
                    u32x2 pk; pk[0] = pack2(acc[fa][fb][0], acc[fa][fb][1]);
                    pk[1] = pack2(acc[fa][fb][2], acc[fa][fb][3]);
                    size_t idx = (((size_t)bb * 32 + (o >> 3)) * 2048 + el) * 8 + (o & 7);
                    *reinterpret_cast<u32x2*>(kb + idx) = pk;
                }
        } else {
#pragma unroll
            for (int fa = 0; fa < 2; ++fa)
#pragma unroll
                for (int fb = 0; fb < 2; ++fb) {
                    int dg = m0 + ar0 + 16 * fa + 4 * half;   // token e
                    int o  = o0 + br0 + 16 * fb + lr;         // out feature
                    int bb = dg >> 11, el = dg & 2047;
                    u32x2 pk; pk[0] = pack2(acc[fa][fb][0], acc[fa][fb][1]);
                    pk[1] = pack2(acc[fa][fb][2], acc[fa][fb][3]);
                    size_t idx = (((size_t)bb * 256 + (el >> 3)) * 256 + o) * 8 + (el & 7);
                    *reinterpret_cast<u32x2*>(vT + idx) = pk;
                }
        }

        if (z < 2) {
            __syncthreads();   // all waves done reading Wt
            const float* Wn = (z == 0) ? Wk : Wv;
#pragma unroll
            for (int i = 0; i < 16; ++i) {
                int fidx = i * 256 + t, row = fidx >> 6, c4 = fidx & 63;
                f32x4 vW = *reinterpret_cast<const f32x4*>(Wn + (size_t)(o0 + row) * NH + c4 * 4);
                u32x2 pw; pw[0] = pack2(vW[0], vW[1]); pw[1] = pack2(vW[2], vW[3]);
                *reinterpret_cast<u32x2*>(&Wt[row][c4 * 4]) = pw;
            }
            __syncthreads();
        }
    }
}

// ---------------------------------------------------------------------------
// Kernel 2: flash attention partials, 32x32x16 MFMA, in-register P.
// 64-e tiles (two 32-e halves per barrier), double-buffered K/V (128KB LDS),
// conflict-free layouts, s_setprio around MFMA clusters.
// ---------------------------------------------------------------------------
template<int ESP, int SIDES>
__global__ __launch_bounds__(512, 2) void attn_kernel(
    const unsigned short* __restrict__ qb, const unsigned short* __restrict__ kb,
    const unsigned short* __restrict__ vT, const int* __restrict__ adj,
    unsigned short* __restrict__ part, float* __restrict__ mpart, float* __restrict__ lpart)
{
    constexpr int GROUPS = 8 / SIDES;
    constexpr int QB = 32 * GROUPS;
    constexpr int NOT = 8 / SIDES;
    constexpr int NT = (ND / ESP) / 64;      // 64-e tiles per block
    constexpr int QTSH = (ESP == 4) ? 5 : 4;

    __shared__ unsigned char KT[2][32768];   // [koct 32][e 64][16B]
    __shared__ unsigned char VTl[2][32768];  // [eoct 8][o 256][16B]

    const int bid = blockIdx.x;
    const int b = bid & 7, es0 = (bid >> 3) & (ESP - 1), qt = bid >> QTSH;
    const int t = threadIdx.x, w = t >> 6, l = t & 63;
    const int lo32 = l & 31, hi = l >> 5;
    const int g = w & (GROUPS - 1), side = w / GROUPS;
    const int qbase = qt * QB + g * 32;
    const int obase = side * (256 / SIDES);
    const int ebase = es0 * (ND / ESP);
    const float SC = 0.0625f, L2E = 1.44269504f;

    bf16x8 qf[16];
    {
        const unsigned short* qr = qb + ((size_t)b * ND + qbase + lo32) * NH + 8 * hi;
#pragma unroll
        for (int kk = 0; kk < 16; ++kk)
            qf[kk] = *reinterpret_cast<const bf16x8*>(qr + kk * 16);
    }

    const char* kbc = (const char*)kb + ((size_t)b << 20);
    const char* vtc = (const char*)vT + ((size_t)b << 20);
    const int* adjr = adj + ((size_t)b * ND + qbase + lo32) * ND + ebase;

    auto stageK = [&](int buf, int tt) {
        const int e0s = ebase + tt * 64;
#pragma unroll
        for (int i = 0; i < 4; ++i) {
            int off = i * 8192 + t * 16;
            int koct = off >> 10, e = (off >> 4) & 63;
            gload_lds16(kbc + (size_t)koct * 32768 + (size_t)(e0s + e) * 16, &KT[buf][off]);
        }
    };
    auto stageV = [&](int buf, int tt) {
        const int Eb = (ebase + tt * 64) >> 3;
#pragma unroll
        for (int i = 0; i < 4; ++i) {
            int off = i * 8192 + t * 16;
            int eoct = off >> 12, o = (off >> 4) & 255;
            gload_lds16(vtc + (size_t)(Eb + eoct) * 4096 + (size_t)o * 16, &VTl[buf][off]);
        }
    };

    f32x16 acc[NOT] = {};
    float m_run = -__builtin_inff(), l_run = 0.f;

    stageK(0, 0); stageV(0, 0);
    __syncthreads();

    for (int tt = 0; tt < NT; ++tt) {
        const int cur = tt & 1;
        if (tt < NT - 1) { stageK(cur ^ 1, tt + 1); stageV(cur ^ 1, tt + 1); }

        const char* Kc = (const char*)&KT[cur][0];
        const char* Vc = (const char*)&VTl[cur][0];

#pragma unroll
        for (int s = 0; s < 2; ++s) {
            i32x4 aj[4];
#pragma unroll
            for (int gg = 0; gg < 4; ++gg)
                aj[gg] = *reinterpret_cast<const i32x4*>(adjr + tt * 64 + s * 32 + gg * 8 + 4 * hi);

            // ---- QK^T for this 32-e half ----
            f32x16 sc = {};
            __builtin_amdgcn_s_setprio(1);
#pragma unroll
            for (int kk = 0; kk < 16; ++kk) {
                bf16x8 kf = *reinterpret_cast<const bf16x8*>(
                    Kc + kk * 2048 + hi * 1024 + s * 512 + lo32 * 16);
                sc = MFMA32(kf, qf[kk], sc, 0, 0, 0);
            }
            __builtin_amdgcn_s_setprio(0);

            // ---- mask + online softmax (defer-max) ----
            float p[16];
            float tmax = -__builtin_inff();
#pragma unroll
            for (int gg = 0; gg < 4; ++gg)
#pragma unroll
                for (int r = 0; r < 4; ++r) {
                    float sv = sc[gg * 4 + r] * SC;
                    sv = (aj[gg][r] > 0) ? sv : -1e9f;
                    p[gg * 4 + r] = sv;
                    tmax = fmaxf(tmax, sv);
                }
            tmax = fmaxf(tmax, __shfl_xor(tmax, 32));
            if (!__all(tmax <= m_run + 8.0f)) {
                const float m_new = fmaxf(m_run, tmax);
                const float scale = exp2f((m_run - m_new) * L2E);
#pragma unroll
                for (int ot = 0; ot < NOT; ++ot)
#pragma unroll
                    for (int r = 0; r < 16; ++r) acc[ot][r] *= scale;
                l_run *= scale;
                m_run = m_new;
            }
            float psum = 0.f;
#pragma unroll
            for (int r2 = 0; r2 < 16; ++r2) {
                float pe = exp2f((p[r2] - m_run) * L2E);
                p[r2] = pe;
                psum += pe;
            }
            psum += __shfl_xor(psum, 32);
            l_run += psum;

            // ---- P -> B-frags in-register ----
            unsigned int c0 = cvtpk(p[0], p[1]),   c1 = cvtpk(p[2], p[3]);
            unsigned int c2 = cvtpk(p[4], p[5]),   c3 = cvtpk(p[6], p[7]);
            plswap(c0, c2); plswap(c1, c3);
            unsigned int c4 = cvtpk(p[8], p[9]),   c5 = cvtpk(p[10], p[11]);
            unsigned int c6 = cvtpk(p[12], p[13]), c7 = cvtpk(p[14], p[15]);
            plswap(c4, c6); plswap(c5, c7);
            const bf16x8 pf0 = mk8(c0, c1, c2, c3);
            const bf16x8 pf1 = mk8(c4, c5, c6, c7);

            // ---- PV ----
            __builtin_amdgcn_s_setprio(1);
#pragma unroll
            for (int ot = 0; ot < NOT; ++ot) {
                bf16x8 vf = *reinterpret_cast<const bf16x8*>(
                    Vc + s * 16384 + hi * 4096 + (size_t)(obase + ot * 32 + lo32) * 16);
                acc[ot] = MFMA32(vf, pf0, acc[ot], 0, 0, 0);
            }
#pragma unroll
            for (int ot = 0; ot < NOT; ++ot) {
                bf16x8 vf = *reinterpret_cast<const bf16x8*>(
                    Vc + s * 16384 + 8192 + hi * 4096 + (size_t)(obase + ot * 32 + lo32) * 16);
                acc[ot] = MFMA32(vf, pf1, acc[ot], 0, 0, 0);
            }
            __builtin_amdgcn_s_setprio(0);
        }
        __syncthreads();
    }

    // ---- epilogue: unnormalized bf16 partials + m/l ----
    const int qg = b * ND + qbase + lo32;
    unsigned short* pb = part + ((size_t)es0 * 16384 + qg) * 256;
#pragma unroll
    for (int ot = 0; ot < NOT; ++ot)
#pragma unroll
        for (int g2 = 0; g2 < 4; ++g2) {
            u32x2 pk;
            pk[0] = pack2(acc[ot][g2 * 4 + 0], acc[ot][g2 * 4 + 1]);
            pk[1] = pack2(acc[ot][g2 * 4 + 2], acc[ot][g2 * 4 + 3]);
            *reinterpret_cast<u32x2*>(pb + obase + ot * 32 + g2 * 8 + 4 * hi) = pk;
        }
    if (hi == 0 && side == 0) {
        mpart[(size_t)es0 * 16384 + qg] = m_run;
        lpart[(size_t)es0 * 16384 + qg] = l_run;
    }
}

// ---------------------------------------------------------------------------
// Kernel 3: fused combine + out-projection + residual + LayerNorm.
// Block = 64 rows. Phase A: per-row softmax-merge coeffs. Phase B: weighted
// partial merge -> Xt (bf16). Phase C: 4 p-chunks GEMM vs Wp -> hL (LDS f32).
// Phase D: += x + bp, LayerNorm, write out.
// ---------------------------------------------------------------------------
template<int ESP>
__global__ __launch_bounds__(256) void fuse_kernel(
    const unsigned short* __restrict__ part, const float* __restrict__ mpart,
    const float* __restrict__ lpart, const float* __restrict__ Wp,
    const float* __restrict__ bp, const float* __restrict__ x,
    const float* __restrict__ gamma, const float* __restrict__ beta,
    float* __restrict__ out)
{
    __shared__ unsigned short Xt[64][264];
    __shared__ unsigned short Wt[64][264];
    __shared__ float hL[64][264];
    __shared__ float cel[64][ESP];

    const int M0 = blockIdx.x * 64;
    const int t = threadIdx.x;
    const float L2E = 1.44269504f;

    // Phase A: merge coefficients per row
    if (t < 64) {
        float me[ESP], le[ESP], M = -__builtin_inff();
#pragma unroll
        for (int e = 0; e < ESP; ++e) {
            me[e] = mpart[(size_t)e * 16384 + M0 + t];
            le[e] = lpart[(size_t)e * 16384 + M0 + t];
            M = fmaxf(M, me[e]);
        }
        float wsum = 0.f;
#pragma unroll
        for (int e = 0; e < ESP; ++e) { me[e] = exp2f((me[e] - M) * L2E); wsum += me[e] * le[e]; }
        const float inv = 1.f / wsum;
#pragma unroll
        for (int e = 0; e < ESP; ++e) cel[t][e] = me[e] * inv;
    }
    // stage Wp chunk 0 (no dependency on cel)
#pragma unroll
    for (int i = 0; i < 16; ++i) {
        int fidx = i * 256 + t, row = fidx >> 6, c4 = fidx & 63;
        f32x4 vW = *reinterpret_cast<const f32x4*>(Wp + (size_t)row * NH + c4 * 4);
        u32x2 pw; pw[0] = pack2(vW[0], vW[1]); pw[1] = pack2(vW[2], vW[3]);
        *reinterpret_cast<u32x2*>(&Wt[row][c4 * 4]) = pw;
    }
    __syncthreads();

    // Phase B: combined agg -> Xt
#pragma unroll
    for (int i = 0; i < 8; ++i) {
        int fidx = i * 256 + t, row = fidx >> 5, c8 = fidx & 31;
        float o[8] = {};
#pragma unroll
        for (int e = 0; e < ESP; ++e) {
            u32x4 v = *reinterpret_cast<const u32x4*>(
                part + (((size_t)e * 16384 + M0 + row) * 256 + c8 * 8));
            const float ce = cel[row][e];
#pragma unroll
            for (int j = 0; j < 4; ++j) {
                o[2 * j]     += ce * bflo(v[j]);
                o[2 * j + 1] += ce * bfhi(v[j]);
            }
        }
        u32x4 pk;
#pragma unroll
        for (int j = 0; j < 4; ++j) pk[j] = pack2(o[2 * j], o[2 * j + 1]);
        *reinterpret_cast<u32x4*>(&Xt[row][c8 * 8]) = pk;
    }
    __syncthreads();

    // Phase C: GEMM over 4 p-chunks
    const int w = t >> 6, lane = t & 63, lr = lane & 15, half = lane >> 4;
    const int ar0 = 32 * (w >> 1), br0 = 32 * (w & 1);

    for (int pc = 0; pc < 4; ++pc) {
        f32x4 acc[2][2] = {};
#pragma unroll
        for (int kk = 0; kk < 8; ++kk) {
            bf16x8 a[2], bfr[2];
#pragma unroll
            for (int f = 0; f < 2; ++f) {
                a[f]   = *reinterpret_cast<const bf16x8*>(&Wt[ar0 + 16 * f + lr][32 * kk + 8 * half]);
                bfr[f] = *reinterpret_cast<const bf16x8*>(&Xt[br0 + 16 * f + lr][32 * kk + 8 * half]);
            }
#pragma unroll
            for (int fa = 0; fa < 2; ++fa)
#pragma unroll
                for (int fb = 0; fb < 2; ++fb)
                    acc[fa][fb] = MFMA16(a[fa], bfr[fb], acc[fa][fb], 0, 0, 0);
        }
#pragma unroll
        for (int fa = 0; fa < 2; ++fa)
#pragma unroll
            for (int fb = 0; fb < 2; ++fb) {
                int p = pc * 64 + ar0 + 16 * fa + 4 * half;
                int m = br0 + 16 * fb + lr;
                *reinterpret_cast<f32x4*>(&hL[m][p]) = acc[fa][fb];
            }
        if (pc < 3) {
            __syncthreads();   // all waves done reading Wt
#pragma unroll
            for (int i = 0; i < 16; ++i) {
                int fidx = i * 256 + t, row = fidx >> 6, c4 = fidx & 63;
                f32x4 vW = *reinterpret_cast<const f32x4*>(
                    Wp + (size_t)((pc + 1) * 64 + row) * NH + c4 * 4);
                u32x2 pw; pw[0] = pack2(vW[0], vW[1]); pw[1] = pack2(vW[2], vW[3]);
                *reinterpret_cast<u32x2*>(&Wt[row][c4 * 4]) = pw;
            }
            __syncthreads();
        }
    }
    __syncthreads();

    // Phase D: residual + bias + LayerNorm, one wave per 16 rows
    f32x4 gm = *reinterpret_cast<const f32x4*>(gamma + lane * 4);
    f32x4 be = *reinterpret_cast<const f32x4*>(beta + lane * 4);
    f32x4 bv = *reinterpret_cast<const f32x4*>(bp + lane * 4);
    for (int rr = 0; rr < 16; ++rr) {
        const int row = w * 16 + rr;
        f32x4 v = *reinterpret_cast<const f32x4*>(&hL[row][lane * 4]);
        f32x4 xr = *reinterpret_cast<const f32x4*>(x + (size_t)(M0 + row) * NH + lane * 4);
#pragma unroll
        for (int r = 0; r < 4; ++r) v[r] += xr[r] + bv[r];
        float s = v[0] + v[1] + v[2] + v[3];
#pragma unroll
        for (int off = 1; off < 64; off <<= 1) s += __shfl_xor(s, off);
        const float mu = s * (1.f / 256.f);
        f32x4 dv; float q = 0.f;
#pragma unroll
        for (int r = 0; r < 4; ++r) { dv[r] = v[r] - mu; q += dv[r] * dv[r]; }
#pragma unroll
        for (int off = 1; off < 64; off <<= 1) q += __shfl_xor(q, off);
        const float rs = rsqrtf(q * (1.f / 256.f) + 1e-5f);
        f32x4 o;
#pragma unroll
        for (int r = 0; r < 4; ++r) o[r] = dv[r] * rs * gm[r] + be[r];
        *reinterpret_cast<f32x4*>(out + (size_t)(M0 + row) * NH + lane * 4) = o;
    }
}

extern "C" void kernel_launch(void* const* d_in, const int* in_sizes, int n_in,
                              void* d_out, int out_size, void* d_ws, size_t ws_size,
                              hipStream_t stream)
{
    const float* x     = (const float*)d_in[0];
    const int*   adj   = (const int*)d_in[1];
    const float* Wq    = (const float*)d_in[2];
    const float* Wk    = (const float*)d_in[3];
    const float* Wv    = (const float*)d_in[4];
    const float* Wp    = (const float*)d_in[5];
    const float* bp    = (const float*)d_in[6];
    const float* gamma = (const float*)d_in[7];
    const float* beta  = (const float*)d_in[8];

    char* ws = (char*)d_ws;
    const size_t MB = 1024 * 1024;
    unsigned short* qb    = (unsigned short*)(ws);
    unsigned short* kb    = (unsigned short*)(ws + 8 * MB);
    unsigned short* vT    = (unsigned short*)(ws + 16 * MB);
    unsigned short* partb = (unsigned short*)(ws + 24 * MB);
    float* out = (float*)d_out;

    qkv_kernel<<<dim3(256, 4), 256, 0, stream>>>(x, Wq, Wk, Wv, qb, kb, vT);

    const bool big = ws_size >= (size_t)57 * MB;
    if (big) {
        float* mpart = (float*)(ws + 56 * MB);
        float* lpart = (float*)(ws + 56 * MB + 256 * 1024);
        attn_kernel<4, 1><<<dim3(256), 512, 0, stream>>>(qb, kb, vT, adj, partb, mpart, lpart);
        fuse_kernel<4><<<dim3(256), 256, 0, stream>>>(partb, mpart, lpart, Wp, bp, x, gamma, beta, out);
    } else {
        float* mpart = (float*)(ws + 40 * MB);
        float* lpart = (float*)(ws + 40 * MB + 128 * 1024);
        attn_kernel<2, 2><<<dim3(256), 512, 0, stream>>>(qb, kb, vT, adj, partb, mpart, lpart);
        fuse_kernel<2><<<dim3(256), 256, 0, stream>>>(partb, mpart, lpart, Wp, bp, x, gamma, beta, out);
    }
}